// Round 1
// baseline (574.653 us; speedup 1.0000x reference)
//
#include <hip/hip_runtime.h>

// GBDT ensemble inference.
// B=32768 rows, T=512 trees, D=8 levels, F=512 features, C=1.
// One block per batch row: x[b,:] (2KB) staged in LDS, each of 256 threads
// walks 2 trees. Tree tables (~4MB total) live in L2/L3 across blocks.

#define BB 32768
#define TT 512
#define DD 8
#define FF 512
#define PAD (TT * 128)   // T * 2^(D-1) = 65536
#define NLV (DD - 1)     // 7 internal levels below the root

__global__ __launch_bounds__(256) void gbdt_ensemble_kernel(
    const float* __restrict__ x,
    const int*   __restrict__ root_nodes,
    const float* __restrict__ root_biases,
    const int*   __restrict__ tree_indices,
    const int*   __restrict__ nodes_lv,
    const float* __restrict__ biases_lv,
    const float* __restrict__ leaf_nodes,
    float*       __restrict__ out)
{
    __shared__ float xs[FF];
    const int b   = blockIdx.x;
    const int tid = threadIdx.x;

    // Coalesced stage of this row's features into LDS (128 float4 = 512 floats).
    const float4* xrow = (const float4*)(x + (size_t)b * FF);
    if (tid < FF / 4) {
        ((float4*)xs)[tid] = xrow[tid];
    }
    __syncthreads();

    // Each thread walks trees t = tid and t = tid + 256 (independent -> ILP).
    #pragma unroll
    for (int k = 0; k < 2; ++k) {
        const int t = tid + k * 256;
        int bit  = (xs[root_nodes[t]] >= root_biases[t]) ? 1 : 0;
        int prev = tree_indices[t] + bit;   // == 2*t + bit
        #pragma unroll
        for (int l = 0; l < NLV; ++l) {
            const int   fi = nodes_lv[(size_t)l * PAD + prev];
            const float th = biases_lv[(size_t)l * PAD + prev];
            bit  = (xs[fi] >= th) ? 1 : 0;
            prev = 2 * prev + bit;
        }
        out[(size_t)b * TT + t] = leaf_nodes[prev];  // C == 1
    }
}

extern "C" void kernel_launch(void* const* d_in, const int* in_sizes, int n_in,
                              void* d_out, int out_size, void* d_ws, size_t ws_size,
                              hipStream_t stream) {
    const float* x            = (const float*)d_in[0];
    const int*   root_nodes   = (const int*)  d_in[1];
    const float* root_biases  = (const float*)d_in[2];
    const int*   tree_indices = (const int*)  d_in[3];
    const int*   nodes_lv     = (const int*)  d_in[4];
    const float* biases_lv    = (const float*)d_in[5];
    const float* leaf_nodes   = (const float*)d_in[6];
    float*       out          = (float*)d_out;

    dim3 grid(BB);
    dim3 block(256);
    gbdt_ensemble_kernel<<<grid, block, 0, stream>>>(
        x, root_nodes, root_biases, tree_indices,
        nodes_lv, biases_lv, leaf_nodes, out);
}

// Round 3
// 104.725 us; speedup vs baseline: 5.4873x; 5.4873x over previous
//
#include <hip/hip_runtime.h>

// GBDT ensemble inference — divergence-optimized mapping.
// B=32768, T=512, D=8, F=512, C=1.
//
// R1 change: lanes index BATCH ROWS (not trees). For a fixed tree t at level l,
// all lanes' node indices fall in t's 2^(l+1)-entry window (<=512B, aligned),
// so each table gather touches 1-8 cache lines instead of 64.
// Block = 1024 threads (16 waves) handles 32 rows x all 512 trees.
//   - x rows staged in LDS (66 KB), each lane reads its own row.
//   - wave w owns trees [w*32, w*32+32); per iteration 2 adjacent trees via
//     lane groups (lane>>5), 2 iterations manually interleaved for MLP.
//   - results transposed through LDS (68 KB) -> coalesced float4 stores.
//   - (feat,bias) packed into int2 in d_ws (one 8B gather per level) when
//     ws_size permits; unpacked fallback otherwise.

#define BB 32768
#define TT 512
#define FF 512
#define PADW 65536        // T * 2^(D-1)
#define NLV 7             // internal levels below root
#define ROWS 32           // batch rows per block
#define THREADS 1024      // 16 waves
#define WAVES 16
#define TPW 32            // trees per wave
#define XSS 516           // xs row stride in floats (pad to de-bank rows)
#define OSS 33            // os tree-local stride (pad)
#define OS_WV (ROWS * OSS)

__global__ __launch_bounds__(256) void pack_tables_kernel(
    const int* __restrict__ nodes_lv, const float* __restrict__ biases_lv,
    int2* __restrict__ packed, int n)
{
    int i = blockIdx.x * 256 + threadIdx.x;
    if (i < n) packed[i] = make_int2(nodes_lv[i], __float_as_int(biases_lv[i]));
}

template<bool PACKED>
__global__ __launch_bounds__(THREADS) void gbdt_walk_kernel(
    const float* __restrict__ x,
    const int*   __restrict__ root_nodes,
    const float* __restrict__ root_biases,
    const int*   __restrict__ tree_indices,
    const int*   __restrict__ nodes_lv,
    const float* __restrict__ biases_lv,
    const float* __restrict__ leaf_nodes,
    const int2*  __restrict__ packed,
    float*       __restrict__ out)
{
    __shared__ float xs[ROWS * XSS];        // 66,048 B
    __shared__ float os[WAVES * OS_WV];     // 67,584 B

    const int tid = threadIdx.x;
    const int b0  = blockIdx.x * ROWS;

    // ---- stage 32 x-rows into LDS (coalesced float4) ----
    const float4* __restrict__ xr = (const float4*)(x + (size_t)b0 * FF);
    #pragma unroll
    for (int i = 0; i < (ROWS * FF / 4) / THREADS; ++i) {   // 4 iters
        int fidx = i * THREADS + tid;       // float4 index over [ROWS][FF/4]
        int r = fidx >> 7, c4 = fidx & 127;
        float4 v = xr[fidx];
        *(float4*)&xs[r * XSS + (c4 << 2)] = v;
    }
    __syncthreads();

    // ---- tree walk: lane = row (&31) + tree-group (>>5) ----
    const int wv   = tid >> 6;              // wave 0..15
    const int lane = tid & 63;
    const int row  = lane & 31;
    const int g    = lane >> 5;             // 2 adjacent trees per instruction
    const int tb   = wv * TPW;
    const float* __restrict__ xrow = &xs[row * XSS];
    float* __restrict__ osw = &os[wv * OS_WV + row * OSS];

    #pragma unroll
    for (int s = 0; s < TPW / 4; ++s) {     // 8 steps, 2 interleaved chains
        const int tlA = 4 * s + g;
        const int tlB = 4 * s + 2 + g;
        const int tA = tb + tlA, tB = tb + tlB;
        int pA = tree_indices[tA] + (xrow[root_nodes[tA]] >= root_biases[tA] ? 1 : 0);
        int pB = tree_indices[tB] + (xrow[root_nodes[tB]] >= root_biases[tB] ? 1 : 0);
        #pragma unroll
        for (int l = 0; l < NLV; ++l) {
            if constexpr (PACKED) {
                const int2 nA = packed[l * PADW + pA];
                const int2 nB = packed[l * PADW + pB];
                pA = 2 * pA + (xrow[nA.x] >= __int_as_float(nA.y) ? 1 : 0);
                pB = 2 * pB + (xrow[nB.x] >= __int_as_float(nB.y) ? 1 : 0);
            } else {
                const int   fA = nodes_lv[l * PADW + pA];
                const int   fB = nodes_lv[l * PADW + pB];
                const float hA = biases_lv[l * PADW + pA];
                const float hB = biases_lv[l * PADW + pB];
                pA = 2 * pA + (xrow[fA] >= hA ? 1 : 0);
                pB = 2 * pB + (xrow[fB] >= hB ? 1 : 0);
            }
        }
        osw[tlA] = leaf_nodes[pA];          // C == 1
        osw[tlB] = leaf_nodes[pB];
    }
    __syncthreads();

    // ---- coalesced flush: [32 rows][512 trees] as float4 ----
    float* __restrict__ orow = out + (size_t)b0 * TT;
    #pragma unroll
    for (int i = 0; i < (ROWS * TT / 4) / THREADS; ++i) {   // 4 iters
        int idx4 = i * THREADS + tid;       // float4 index over [ROWS][TT/4]
        int r = idx4 >> 7, t4 = idx4 & 127;
        int t = t4 << 2;                    // 4-aligned -> same wave slab
        const float* o = &os[(t >> 5) * OS_WV + r * OSS + (t & 31)];
        *(float4*)&orow[(size_t)r * TT + t] = make_float4(o[0], o[1], o[2], o[3]);
    }
}

extern "C" void kernel_launch(void* const* d_in, const int* in_sizes, int n_in,
                              void* d_out, int out_size, void* d_ws, size_t ws_size,
                              hipStream_t stream) {
    const float* x            = (const float*)d_in[0];
    const int*   root_nodes   = (const int*)  d_in[1];
    const float* root_biases  = (const float*)d_in[2];
    const int*   tree_indices = (const int*)  d_in[3];
    const int*   nodes_lv     = (const int*)  d_in[4];
    const float* biases_lv    = (const float*)d_in[5];
    const float* leaf_nodes   = (const float*)d_in[6];
    float*       out          = (float*)d_out;

    const int n_nodes = NLV * PADW;                     // 458,752
    const size_t packed_bytes = (size_t)n_nodes * 8;    // 3.67 MB

    dim3 grid(BB / ROWS);   // 1024 blocks
    dim3 block(THREADS);

    if (ws_size >= packed_bytes) {
        int2* packed = (int2*)d_ws;
        pack_tables_kernel<<<(n_nodes + 255) / 256, 256, 0, stream>>>(
            nodes_lv, biases_lv, packed, n_nodes);
        gbdt_walk_kernel<true><<<grid, block, 0, stream>>>(
            x, root_nodes, root_biases, tree_indices,
            nodes_lv, biases_lv, leaf_nodes, packed, out);
    } else {
        gbdt_walk_kernel<false><<<grid, block, 0, stream>>>(
            x, root_nodes, root_biases, tree_indices,
            nodes_lv, biases_lv, leaf_nodes, (const int2*)nullptr, out);
    }
}

// Round 4
// 99.106 us; speedup vs baseline: 5.7984x; 1.0567x over previous
//
#include <hip/hip_runtime.h>

// GBDT ensemble inference — divergence-optimized mapping, occupancy-tuned.
// B=32768, T=512, D=8, F=512, C=1.
//
// R3 change: ROWS 32->16 so LDS = 67 KB -> 2 blocks/CU (occupancy 42%->~84%),
// doubling outstanding dependent-chain gathers per SIMD. Lane layout is now
// 16 rows x 4 adjacent-tree groups (windows stay contiguous). VGPR pinned
// <=64 via __launch_bounds__(1024, 8) so 2 blocks actually fit.

#define BB 32768
#define TT 512
#define FF 512
#define PADW 65536        // T * 2^(D-1)
#define NLV 7             // internal levels below root
#define ROWS 16           // batch rows per block
#define THREADS 1024      // 16 waves
#define WAVES 16
#define TPW 32            // trees per wave
#define XSS 516           // xs row stride in floats (pad to de-bank rows)
#define OSS 33            // os tree-local stride (pad)
#define OS_WV (ROWS * OSS)  // 528

__global__ __launch_bounds__(256) void pack_tables_kernel(
    const int* __restrict__ nodes_lv, const float* __restrict__ biases_lv,
    int2* __restrict__ packed, int n)
{
    int i = blockIdx.x * 256 + threadIdx.x;
    if (i < n) packed[i] = make_int2(nodes_lv[i], __float_as_int(biases_lv[i]));
}

template<bool PACKED>
__global__ __launch_bounds__(THREADS, 8) void gbdt_walk_kernel(
    const float* __restrict__ x,
    const int*   __restrict__ root_nodes,
    const float* __restrict__ root_biases,
    const int*   __restrict__ tree_indices,
    const int*   __restrict__ nodes_lv,
    const float* __restrict__ biases_lv,
    const float* __restrict__ leaf_nodes,
    const int2*  __restrict__ packed,
    float*       __restrict__ out)
{
    __shared__ float xs[ROWS * XSS];        // 33,024 B
    __shared__ float os[WAVES * OS_WV];     // 33,792 B   (total 66,816 B)

    const int tid = threadIdx.x;
    const int b0  = blockIdx.x * ROWS;

    // ---- stage 16 x-rows into LDS (coalesced float4, 2 iters) ----
    const float4* __restrict__ xr = (const float4*)(x + (size_t)b0 * FF);
    #pragma unroll
    for (int i = 0; i < (ROWS * FF / 4) / THREADS; ++i) {   // 2 iters
        int fidx = i * THREADS + tid;       // float4 index over [ROWS][FF/4]
        int r = fidx >> 7, c4 = fidx & 127;
        float4 v = xr[fidx];
        *(float4*)&xs[r * XSS + (c4 << 2)] = v;
    }
    __syncthreads();

    // ---- tree walk: lane = row (&15) + tree-group (>>4, 4 adjacent trees) ----
    const int wv   = tid >> 6;              // wave 0..15
    const int lane = tid & 63;
    const int row  = lane & 15;
    const int g    = lane >> 4;             // 0..3: 4 adjacent trees/instruction
    const int tb   = wv * TPW;
    const float* __restrict__ xrow = &xs[row * XSS];
    float* __restrict__ osw = &os[wv * OS_WV + row * OSS];

    #pragma unroll
    for (int s = 0; s < TPW / 8; ++s) {     // 4 steps, 2 interleaved chains
        const int tlA = 8 * s + g;
        const int tlB = 8 * s + 4 + g;
        const int tA = tb + tlA, tB = tb + tlB;
        int pA = tree_indices[tA] + (xrow[root_nodes[tA]] >= root_biases[tA] ? 1 : 0);
        int pB = tree_indices[tB] + (xrow[root_nodes[tB]] >= root_biases[tB] ? 1 : 0);
        #pragma unroll
        for (int l = 0; l < NLV; ++l) {
            if constexpr (PACKED) {
                const int2 nA = packed[l * PADW + pA];
                const int2 nB = packed[l * PADW + pB];
                pA = 2 * pA + (xrow[nA.x] >= __int_as_float(nA.y) ? 1 : 0);
                pB = 2 * pB + (xrow[nB.x] >= __int_as_float(nB.y) ? 1 : 0);
            } else {
                const int   fA = nodes_lv[l * PADW + pA];
                const int   fB = nodes_lv[l * PADW + pB];
                const float hA = biases_lv[l * PADW + pA];
                const float hB = biases_lv[l * PADW + pB];
                pA = 2 * pA + (xrow[fA] >= hA ? 1 : 0);
                pB = 2 * pB + (xrow[fB] >= hB ? 1 : 0);
            }
        }
        osw[tlA] = leaf_nodes[pA];          // C == 1
        osw[tlB] = leaf_nodes[pB];
    }
    __syncthreads();

    // ---- coalesced flush: [16 rows][512 trees] as float4 (2 iters) ----
    float* __restrict__ orow = out + (size_t)b0 * TT;
    #pragma unroll
    for (int i = 0; i < (ROWS * TT / 4) / THREADS; ++i) {   // 2 iters
        int idx4 = i * THREADS + tid;       // float4 index over [ROWS][TT/4]
        int r = idx4 >> 7, t4 = idx4 & 127;
        int t = t4 << 2;                    // 4-aligned -> same wave slab
        const float* o = &os[(t >> 5) * OS_WV + r * OSS + (t & 31)];
        *(float4*)&orow[(size_t)r * TT + t] = make_float4(o[0], o[1], o[2], o[3]);
    }
}

extern "C" void kernel_launch(void* const* d_in, const int* in_sizes, int n_in,
                              void* d_out, int out_size, void* d_ws, size_t ws_size,
                              hipStream_t stream) {
    const float* x            = (const float*)d_in[0];
    const int*   root_nodes   = (const int*)  d_in[1];
    const float* root_biases  = (const float*)d_in[2];
    const int*   tree_indices = (const int*)  d_in[3];
    const int*   nodes_lv     = (const int*)  d_in[4];
    const float* biases_lv    = (const float*)d_in[5];
    const float* leaf_nodes   = (const float*)d_in[6];
    float*       out          = (float*)d_out;

    const int n_nodes = NLV * PADW;                     // 458,752
    const size_t packed_bytes = (size_t)n_nodes * 8;    // 3.67 MB

    dim3 grid(BB / ROWS);   // 2048 blocks
    dim3 block(THREADS);

    if (ws_size >= packed_bytes) {
        int2* packed = (int2*)d_ws;
        pack_tables_kernel<<<(n_nodes + 255) / 256, 256, 0, stream>>>(
            nodes_lv, biases_lv, packed, n_nodes);
        gbdt_walk_kernel<true><<<grid, block, 0, stream>>>(
            x, root_nodes, root_biases, tree_indices,
            nodes_lv, biases_lv, leaf_nodes, packed, out);
    } else {
        gbdt_walk_kernel<false><<<grid, block, 0, stream>>>(
            x, root_nodes, root_biases, tree_indices,
            nodes_lv, biases_lv, leaf_nodes, (const int2*)nullptr, out);
    }
}